// Round 6
// baseline (801.949 us; speedup 1.0000x reference)
//
#include <hip/hip_runtime.h>
#include <hip/hip_bf16.h>

// B=64, T=60 (40 enc + 20 dec), H=512, E=512, V=32000. fp32 I/O.
// Compute: bf16 MFMA (fp32 accum), on-the-fly fp32->bf16 in staging.
//
//   1) gemm_xproj: Xp[3840][2048] = xs @ W_ih^T + (b_ih+b_hh); xs built on the
//      fly (zero-pad | embedding gather | feature). Xp fp32 lives in d_out
//      (dead before GEMM2 overwrites d_out).
//   2) lstm_persist (ONE kernel, 32 blocks): W_hh slice resident in LDS (64KB,
//      loaded once, XOR-swizzled -> bank-conflict-free B-reads), c in VGPRs,
//      h ping-pong in ws. Cross-block coherence is PER-ACCESS (agent-scope
//      relaxed atomics; write-through stores / L2-bypass loads) — no
//      threadfence/L2 flush. Barrier = per-block flag publish + bounded spin.
//      r5: Xp prefetch for t+1 moved to the TOP of step t (right after the
//      h-load batch). Previously it was issued just before __syncthreads,
//      whose vmcnt(0) drain then serialized a fresh HBM RTT (~0.9us) into
//      the publish path of every block, every step. Now the prefetch
//      completes under the MFMA+cell window and the drain waits only on
//      store-acks. (r6 = r5 resubmitted unchanged; r5 bench was an infra
//      failure with the same signature as r1, which passed on resubmit.)
//   3) gemm_out: out[1216][32000] = dec_h @ W_lin^T + b_lin, fp32 out.
//      If ws_size permits, W_lin is pre-converted to bf16 once (cvt_bf16) and
//      GEMM2 stages pure int4; else fallback converts inline.

typedef short bf16x8 __attribute__((ext_vector_type(8)));
typedef float f32x4 __attribute__((ext_vector_type(4)));

__device__ inline short f2bf(float f) {
    unsigned u = __float_as_uint(f);
    unsigned r = (u + 0x7fffu + ((u >> 16) & 1u)) >> 16;   // RNE
    return (short)r;
}
__device__ inline int4 ld8_f32_to_bf16(const float* __restrict__ g) {
    float4 a = *(const float4*)g;
    float4 b = *(const float4*)(g + 4);
    union { short s[8]; int4 v; } u;
    u.s[0] = f2bf(a.x); u.s[1] = f2bf(a.y); u.s[2] = f2bf(a.z); u.s[3] = f2bf(a.w);
    u.s[4] = f2bf(b.x); u.s[5] = f2bf(b.y); u.s[6] = f2bf(b.z); u.s[7] = f2bf(b.w);
    return u.v;
}
__device__ inline float sigf(float x) { return 1.0f / (1.0f + expf(-x)); }

// fast activations for the LSTM cell (error ~1e-6, << bf16 rounding of h):
__device__ inline float sig_fast(float x) {
    return __builtin_amdgcn_rcpf(1.0f + __expf(-x));
}
__device__ inline float tanh_fast(float x) {
    // tanh(x) = 1 - 2/(e^{2x}+1); saturates correctly at +-inf
    return 1.0f - 2.0f * __builtin_amdgcn_rcpf(1.0f + __expf(2.0f * x));
}

// ---------------------------------------------------------------------------
// GEMM1 (fused xs build): Xp[3840][2048] = xs @ W_ih^T + (b_ih + b_hh), fp32.
// ---------------------------------------------------------------------------
__global__ __launch_bounds__(256) void gemm_xproj(
    const float* __restrict__ feature,    // [64][60][512]
    const int*   __restrict__ captions,   // [64][20]
    const float* __restrict__ embedding,  // [32000][512]
    const float* __restrict__ W_ih,       // [2048][1024]
    const float* __restrict__ b_ih,
    const float* __restrict__ b_hh,
    float* __restrict__ Xp)               // [3840][2048]
{
    __shared__ __align__(16) short Al[128 * 72];
    __shared__ __align__(16) short Bl[128 * 72];
    const int tid  = threadIdx.x;
    const int wave = tid >> 6, lane = tid & 63;
    const int quad = lane >> 4, l16 = lane & 15;
    const int m0 = blockIdx.y * 128;
    const int n0 = blockIdx.x * 128;
    const int wm = (wave >> 1) * 64, wn = (wave & 1) * 64;
    const int sr = tid >> 3;
    const int sc = (tid & 7) * 8;

    f32x4 acc[4][4] = {};

    for (int k0 = 0; k0 < 1024; k0 += 64) {
        const int j = k0 + sc;
#pragma unroll
        for (int p = 0; p < 4; ++p) {
            int r = sr + p * 32;
            int row = m0 + r;
            int t = row >> 6, b = row & 63;
            int4 val;
            if (j < 512) {
                if (t >= 40) {
                    int tok = captions[b * 20 + (t - 40)];
                    val = ld8_f32_to_bf16(&embedding[(size_t)tok * 512 + j]);
                } else {
                    val = make_int4(0, 0, 0, 0);
                }
            } else {
                val = ld8_f32_to_bf16(&feature[(size_t)(b * 60 + t) * 512 + (j - 512)]);
            }
            *(int4*)&Al[r * 72 + sc] = val;
            *(int4*)&Bl[r * 72 + sc] = ld8_f32_to_bf16(&W_ih[(size_t)(n0 + r) * 1024 + j]);
        }
        __syncthreads();
#pragma unroll
        for (int kk = 0; kk < 64; kk += 32) {
            bf16x8 af[4], bg[4];
#pragma unroll
            for (int i = 0; i < 4; ++i)
                af[i] = *(const bf16x8*)&Al[(wm + i * 16 + l16) * 72 + kk + quad * 8];
#pragma unroll
            for (int jj = 0; jj < 4; ++jj)
                bg[jj] = *(const bf16x8*)&Bl[(wn + jj * 16 + l16) * 72 + kk + quad * 8];
#pragma unroll
            for (int i = 0; i < 4; ++i)
#pragma unroll
                for (int jj = 0; jj < 4; ++jj)
                    acc[i][jj] = __builtin_amdgcn_mfma_f32_16x16x32_bf16(
                        af[i], bg[jj], acc[i][jj], 0, 0, 0);
        }
        __syncthreads();
    }

#pragma unroll
    for (int jj = 0; jj < 4; ++jj) {
        int n = n0 + wn + jj * 16 + l16;
        float bv = b_ih[n] + b_hh[n];
#pragma unroll
        for (int i = 0; i < 4; ++i) {
            int mbase = m0 + wm + i * 16 + quad * 4;
#pragma unroll
            for (int r = 0; r < 4; ++r)
                Xp[(size_t)(mbase + r) * 2048 + n] = acc[i][jj][r] + bv;
        }
    }
}

// ---------------------------------------------------------------------------
// W_lin fp32 -> bf16 pre-convert
// ---------------------------------------------------------------------------
__global__ __launch_bounds__(256) void cvt_bf16(
    const float* __restrict__ src, short* __restrict__ dst, int n8)
{
    int i = blockIdx.x * 256 + threadIdx.x;
    if (i < n8)
        *(int4*)&dst[(size_t)i * 8] = ld8_f32_to_bf16(&src[(size_t)i * 8]);
}

// ---------------------------------------------------------------------------
// GEMM2: out[M][N] = A(bf16) @ W[N][K]^T + bias(f32), fp32 out, M-guard.
// BF16B: W already bf16 (pre-converted); else fp32 with inline conversion.
// ---------------------------------------------------------------------------
template <bool BF16B>
__global__ __launch_bounds__(256) void gemm_out(
    const short* __restrict__ A,       // M x K bf16
    const void*  __restrict__ Wv,      // N x K (bf16 or f32)
    const float* __restrict__ bias,    // N
    float* __restrict__ C,
    int M, int N, int K)
{
    __shared__ __align__(16) short Al[128 * 72];
    __shared__ __align__(16) short Bl[128 * 72];
    const int tid  = threadIdx.x;
    const int wave = tid >> 6, lane = tid & 63;
    const int quad = lane >> 4, l16 = lane & 15;
    const int m0 = blockIdx.y * 128;
    const int n0 = blockIdx.x * 128;
    const int wm = (wave >> 1) * 64, wn = (wave & 1) * 64;
    const int sr = tid >> 3;
    const int sc = (tid & 7) * 8;

    f32x4 acc[4][4] = {};

    for (int k0 = 0; k0 < K; k0 += 64) {
#pragma unroll
        for (int p = 0; p < 4; ++p) {
            int r = sr + p * 32;
            int am = m0 + r;
            am = (am < M) ? am : (M - 1);
            *(int4*)&Al[r * 72 + sc] = *(const int4*)&A[(size_t)am * K + k0 + sc];
            if (BF16B)
                *(int4*)&Bl[r * 72 + sc] =
                    *(const int4*)&((const short*)Wv)[(size_t)(n0 + r) * K + k0 + sc];
            else
                *(int4*)&Bl[r * 72 + sc] =
                    ld8_f32_to_bf16(&((const float*)Wv)[(size_t)(n0 + r) * K + k0 + sc]);
        }
        __syncthreads();
#pragma unroll
        for (int kk = 0; kk < 64; kk += 32) {
            bf16x8 af[4], bg[4];
#pragma unroll
            for (int i = 0; i < 4; ++i)
                af[i] = *(const bf16x8*)&Al[(wm + i * 16 + l16) * 72 + kk + quad * 8];
#pragma unroll
            for (int jj = 0; jj < 4; ++jj)
                bg[jj] = *(const bf16x8*)&Bl[(wn + jj * 16 + l16) * 72 + kk + quad * 8];
#pragma unroll
            for (int i = 0; i < 4; ++i)
#pragma unroll
                for (int jj = 0; jj < 4; ++jj)
                    acc[i][jj] = __builtin_amdgcn_mfma_f32_16x16x32_bf16(
                        af[i], bg[jj], acc[i][jj], 0, 0, 0);
        }
        __syncthreads();
    }

#pragma unroll
    for (int jj = 0; jj < 4; ++jj) {
        int n = n0 + wn + jj * 16 + l16;
        float bv = bias[n];
#pragma unroll
        for (int i = 0; i < 4; ++i) {
            int mbase = m0 + wm + i * 16 + quad * 4;
#pragma unroll
            for (int r = 0; r < 4; ++r) {
                int m = mbase + r;
                if (m < M)
                    C[(size_t)m * N + n] = acc[i][jj][r] + bv;
            }
        }
    }
}

// ---------------------------------------------------------------------------
// Persistent LSTM: 32 blocks x 256 thr. Block bx owns h-cols [16bx,16bx+16)
// (gate-cols {s*512+16bx..}, s=0..3). W_hh slice (64x512, bf16) in LDS,
// XOR-swizzled (r3: killed the 16-way conflict). c in VGPRs. h ping-pongs in
// global (bf16): write-through u64 agent stores / L2-bypass u64 agent loads.
// No threadfence anywhere. Barrier: flags[bid]=t+1 after __syncthreads (which
// drains vmcnt -> stores at coherence point); wave-0 lanes spin (bounded).
// r4: h-loads issued as ONE batch behind sched_barrier(0) -> 1 MALL RTT.
// r5: Xp prefetch issued at TOP of step (after h-load batch), so the
// pre-flag vmcnt drain no longer serializes an HBM RTT into the publish path.
// __launch_bounds__(256,1): grid=32, 1 block/CU; no VGPR cap.
// ---------------------------------------------------------------------------
#define LSTM_BLOCKS 32

__global__ __launch_bounds__(256, 1) void lstm_persist(
    const float* __restrict__ Xp,     // [59][64][2048] fp32 (in d_out)
    const float* __restrict__ W_hh,   // [2048][512] fp32
    unsigned long long* __restrict__ hbuf, // [2][64][512] bf16 ping-pong
    unsigned long long* __restrict__ dec_h, // [1216][512] bf16 (row = b*19+dec)
    unsigned* __restrict__ flags)     // [32] zeroed per launch
{
    __shared__ __align__(16) short Wl[64 * 512];   // 64 KB, swizzled layout
    __shared__ __align__(16) short Ht[4][16][16];  // 2 KB: per-wave h tile
    const int tid  = threadIdx.x;
    const int wave = tid >> 6, lane = tid & 63;
    const int quad = lane >> 4, l16 = lane & 15;
    const int nb = blockIdx.x * 16;
    const int swz = (l16 & 7) << 3;                // read-side XOR (shorts)

    // one-time: W slice -> LDS (row rr = s*16+col <-> W_hh row s*512+nb+col)
    // write-side XOR uses rr (wave-uniform) -> conflict-free.
#pragma unroll
    for (int it = 0; it < 16; ++it) {
        int rr = (tid >> 6) + it * 4;          // 0..63
        int k  = (tid & 63) * 8;               // 0..504
        int s = rr >> 4, col = rr & 15;
        *(int4*)&Wl[(rr * 512 + k) ^ ((rr & 7) << 3)] =
            ld8_f32_to_bf16(&W_hh[(size_t)(s * 512 + nb + col) * 512 + k]);
    }
    float creg[4] = {0.f, 0.f, 0.f, 0.f};

    // Xp prefetch for t=0 (overlaps the W-LDS staging)
    const int n = nb + l16;
    float xg[4][4];
#pragma unroll
    for (int r = 0; r < 4; ++r) {
        const float* xr = Xp + (size_t)(wave * 16 + quad * 4 + r) * 2048;
        xg[r][0] = xr[n];
        xg[r][1] = xr[512 + n];
        xg[r][2] = xr[1024 + n];
        xg[r][3] = xr[1536 + n];
    }
    __syncthreads();

    for (int t = 0; t < 59; ++t) {
        // --- region A: issue the h-load batch (one MALL RTT for all 32) ---
        union { unsigned long long q[2]; bf16x8 v; } hu[16];
        if (t > 0) {
            const unsigned long long* hrow =
                hbuf + ((size_t)((t & 1) ^ 1) << 13)          // slot * 8192 u64
                     + (size_t)(wave * 16 + l16) * 128 + quad * 2;
#pragma unroll
            for (int kk = 0; kk < 16; ++kk) {
                hu[kk].q[0] = __hip_atomic_load(&hrow[kk * 8],
                                 __ATOMIC_RELAXED, __HIP_MEMORY_SCOPE_AGENT);
                hu[kk].q[1] = __hip_atomic_load(&hrow[kk * 8 + 1],
                                 __ATOMIC_RELAXED, __HIP_MEMORY_SCOPE_AGENT);
            }
        }
        __builtin_amdgcn_sched_barrier(0);   // h-loads issued first

        // --- region B: issue Xp prefetch for t+1 NOW (younger in vmcnt, so
        // the MFMA's wait on hu doesn't wait for these; they complete under
        // the MFMA+cell window and are free by the pre-flag drain) ---
        float xn_[4][4];
        if (t < 58) {
            const float* xt = Xp + (size_t)(t + 1) * 131072;
#pragma unroll
            for (int r = 0; r < 4; ++r) {
                const float* xr = xt + (size_t)(wave * 16 + quad * 4 + r) * 2048;
                xn_[r][0] = xr[n];
                xn_[r][1] = xr[512 + n];
                xn_[r][2] = xr[1024 + n];
                xn_[r][3] = xr[1536 + n];
            }
        }
        __builtin_amdgcn_sched_barrier(0);   // prefetch issued before MFMA

        // --- region C: recurrent MFMA ---
        f32x4 acc[4] = {};
        if (t > 0) {
#pragma unroll
            for (int kk = 0; kk < 16; ++kk) {
#pragma unroll
                for (int s = 0; s < 4; ++s) {
                    bf16x8 bg = *(const bf16x8*)
                        &Wl[((s * 16 + l16) * 512 + kk * 32 + quad * 8) ^ swz];
                    acc[s] = __builtin_amdgcn_mfma_f32_16x16x32_bf16(hu[kk].v, bg, acc[s], 0, 0, 0);
                }
            }
        }

        // --- region D: cell update (C-layout: row = quad*4+r, col = l16) ---
#pragma unroll
        for (int r = 0; r < 4; ++r) {
            float iv = acc[0][r] + xg[r][0];
            float fv = acc[1][r] + xg[r][1];
            float gv = acc[2][r] + xg[r][2];
            float ov = acc[3][r] + xg[r][3];
            float cn = sig_fast(fv) * creg[r] + sig_fast(iv) * tanh_fast(gv);
            float hn = sig_fast(ov) * tanh_fast(cn);
            creg[r] = cn;
            Ht[wave][quad * 4 + r][l16] = f2bf(hn);
        }
        asm volatile("s_waitcnt lgkmcnt(0)" ::: "memory");  // wave-local tile ready
        // publish tile: ONE aligned u64 write-through store per thread
        unsigned long long* hout64 = hbuf + ((size_t)(t & 1) << 13);
        {
            int row = lane >> 2, qp = lane & 3;    // row 0..15, u64-in-row 0..3
            unsigned long long v = *(const unsigned long long*)&Ht[wave][row][qp * 4];
            int m = wave * 16 + row;
            __hip_atomic_store(&hout64[m * 128 + (nb >> 2) + qp], v,
                               __ATOMIC_RELAXED, __HIP_MEMORY_SCOPE_AGENT);
            if (t >= 40)
                dec_h[(size_t)(m * 19 + (t - 40)) * 128 + (nb >> 2) + qp] = v;
        }

        // --- region E: global step barrier ---
        if (t < 58) {
            // __syncthreads drains vmcnt(0) in every thread -> all h stores
            // of this block are at the coherence point before the flag store.
            // (Xp prefetch was issued at the top of the step and is done.)
            __syncthreads();
            if (tid == 0)
                __hip_atomic_store(&flags[blockIdx.x], (unsigned)(t + 1),
                                   __ATOMIC_RELAXED, __HIP_MEMORY_SCOPE_AGENT);
            if (tid < LSTM_BLOCKS) {
                int guard = 0;
                while (__hip_atomic_load(&flags[tid], __ATOMIC_RELAXED,
                                         __HIP_MEMORY_SCOPE_AGENT) < (unsigned)(t + 1)
                       && guard < (1 << 16)) {   // bounded: fail visibly, not hang
                    __builtin_amdgcn_s_sleep(1);
                    ++guard;
                }
            }
            __syncthreads();
#pragma unroll
            for (int r = 0; r < 4; ++r)
#pragma unroll
                for (int g = 0; g < 4; ++g)
                    xg[r][g] = xn_[r][g];
        }
    }
}

// ---------------------------------------------------------------------------
extern "C" void kernel_launch(void* const* d_in, const int* in_sizes, int n_in,
                              void* d_out, int out_size, void* d_ws, size_t ws_size,
                              hipStream_t stream)
{
    (void)in_sizes; (void)n_in; (void)out_size;
    const float* feature   = (const float*)d_in[0];
    const int*   captions  = (const int*)d_in[1];
    const float* embedding = (const float*)d_in[2];
    const float* W_ih      = (const float*)d_in[3];
    const float* W_hh      = (const float*)d_in[4];
    const float* b_ih      = (const float*)d_in[5];
    const float* b_hh      = (const float*)d_in[6];
    const float* W_lin     = (const float*)d_in[7];
    const float* b_lin     = (const float*)d_in[8];
    float* out = (float*)d_out;

    // ws layout
    char* ws = (char*)d_ws;
    unsigned long long* hbuf = (unsigned long long*)(ws); // 2*64*512*2 = 131,072 B
    short*    dech = (short*)(ws + 131072);        // 1216*512*2   = 1,245,184 B
    unsigned* flags = (unsigned*)(ws + 1376256);   // 128 B (32 x u32)
    short*    wbf  = (short*)(ws + 1376512);       // 32000*512*2  = 32,768,000 B
    const bool big = ws_size >= (size_t)1376512 + 32768000;

    // fp32 X_proj lives in d_out (31.5 MB of 155.6 MB); dead before GEMM2.
    float* Xp = (float*)d_out;

    hipMemsetAsync(flags, 0, 256, stream);

    if (big)
        cvt_bf16<<<8000, 256, 0, stream>>>(W_lin, wbf, 2048000);

    gemm_xproj<<<dim3(16, 30), 256, 0, stream>>>(
        feature, captions, embedding, W_ih, b_ih, b_hh, Xp);

    lstm_persist<<<LSTM_BLOCKS, 256, 0, stream>>>(
        Xp, W_hh, hbuf, (unsigned long long*)dech, flags);

    if (big)
        gemm_out<true><<<dim3(250, 10), 256, 0, stream>>>(
            dech, wbf, b_lin, out, 1216, 32000, 512);
    else
        gemm_out<false><<<dim3(250, 10), 256, 0, stream>>>(
            dech, W_lin, b_lin, out, 1216, 32000, 512);
}

// Round 7
// 747.338 us; speedup vs baseline: 1.0731x; 1.0731x over previous
//
#include <hip/hip_runtime.h>
#include <hip/hip_bf16.h>

// B=64, T=60 (40 enc + 20 dec), H=512, E=512, V=32000. fp32 I/O.
// Compute: bf16 MFMA (fp32 accum), on-the-fly fp32->bf16 in staging.
//
//   1) gemm_xproj: Xp[3840][2048] = xs @ W_ih^T + (b_ih+b_hh); xs built on the
//      fly (zero-pad | embedding gather | feature). Xp fp32 lives in d_out
//      (dead before GEMM2 overwrites d_out).
//   2) lstm_persist (ONE kernel, 32 blocks): W_hh slice resident in LDS (64KB,
//      loaded once, XOR-swizzled -> bank-conflict-free B-reads), c in VGPRs,
//      h ping-pong in ws. Cross-block coherence is PER-ACCESS (agent-scope
//      relaxed atomics; write-through stores / L2-bypass loads) — no
//      threadfence/L2 flush. Barrier = per-block flag publish + bounded spin.
//      r7: reverted to the r4 step schedule (Xp prefetch AFTER publish, where
//      it overlaps the store-ack drain). r5's prefetch-at-top stretched the
//      h-load critical path (333 -> 376 us, measured) — reverted.
//   3) gemm_out: out[1216][32000] = dec_h @ W_lin^T + b_lin, fp32 out.
//      r7: BF16B path stages A/B tiles via global_load_lds width=16 with
//      rule-#21 both-sides XOR swizzle (linear LDS dest + inverse-swizzled
//      global source + swizzled ds_read). No pad, no reg round-trip.
//      Fallback (small ws) keeps the old reg-staged padded path.

typedef short bf16x8 __attribute__((ext_vector_type(8)));
typedef float f32x4 __attribute__((ext_vector_type(4)));

__device__ inline short f2bf(float f) {
    unsigned u = __float_as_uint(f);
    unsigned r = (u + 0x7fffu + ((u >> 16) & 1u)) >> 16;   // RNE
    return (short)r;
}
__device__ inline int4 ld8_f32_to_bf16(const float* __restrict__ g) {
    float4 a = *(const float4*)g;
    float4 b = *(const float4*)(g + 4);
    union { short s[8]; int4 v; } u;
    u.s[0] = f2bf(a.x); u.s[1] = f2bf(a.y); u.s[2] = f2bf(a.z); u.s[3] = f2bf(a.w);
    u.s[4] = f2bf(b.x); u.s[5] = f2bf(b.y); u.s[6] = f2bf(b.z); u.s[7] = f2bf(b.w);
    return u.v;
}
__device__ inline float sigf(float x) { return 1.0f / (1.0f + expf(-x)); }

// fast activations for the LSTM cell (error ~1e-6, << bf16 rounding of h):
__device__ inline float sig_fast(float x) {
    return __builtin_amdgcn_rcpf(1.0f + __expf(-x));
}
__device__ inline float tanh_fast(float x) {
    // tanh(x) = 1 - 2/(e^{2x}+1); saturates correctly at +-inf
    return 1.0f - 2.0f * __builtin_amdgcn_rcpf(1.0f + __expf(2.0f * x));
}

// direct global->LDS DMA, 16B per lane (dest = wave-uniform base + lane*16)
__device__ inline void gload_lds16(const void* g, void* l) {
    __builtin_amdgcn_global_load_lds(
        (const __attribute__((address_space(1))) void*)g,
        (__attribute__((address_space(3))) void*)l, 16, 0, 0);
}

// ---------------------------------------------------------------------------
// GEMM1 (fused xs build): Xp[3840][2048] = xs @ W_ih^T + (b_ih + b_hh), fp32.
// ---------------------------------------------------------------------------
__global__ __launch_bounds__(256) void gemm_xproj(
    const float* __restrict__ feature,    // [64][60][512]
    const int*   __restrict__ captions,   // [64][20]
    const float* __restrict__ embedding,  // [32000][512]
    const float* __restrict__ W_ih,       // [2048][1024]
    const float* __restrict__ b_ih,
    const float* __restrict__ b_hh,
    float* __restrict__ Xp)               // [3840][2048]
{
    __shared__ __align__(16) short Al[128 * 72];
    __shared__ __align__(16) short Bl[128 * 72];
    const int tid  = threadIdx.x;
    const int wave = tid >> 6, lane = tid & 63;
    const int quad = lane >> 4, l16 = lane & 15;
    const int m0 = blockIdx.y * 128;
    const int n0 = blockIdx.x * 128;
    const int wm = (wave >> 1) * 64, wn = (wave & 1) * 64;
    const int sr = tid >> 3;
    const int sc = (tid & 7) * 8;

    f32x4 acc[4][4] = {};

    for (int k0 = 0; k0 < 1024; k0 += 64) {
        const int j = k0 + sc;
#pragma unroll
        for (int p = 0; p < 4; ++p) {
            int r = sr + p * 32;
            int row = m0 + r;
            int t = row >> 6, b = row & 63;
            int4 val;
            if (j < 512) {
                if (t >= 40) {
                    int tok = captions[b * 20 + (t - 40)];
                    val = ld8_f32_to_bf16(&embedding[(size_t)tok * 512 + j]);
                } else {
                    val = make_int4(0, 0, 0, 0);
                }
            } else {
                val = ld8_f32_to_bf16(&feature[(size_t)(b * 60 + t) * 512 + (j - 512)]);
            }
            *(int4*)&Al[r * 72 + sc] = val;
            *(int4*)&Bl[r * 72 + sc] = ld8_f32_to_bf16(&W_ih[(size_t)(n0 + r) * 1024 + j]);
        }
        __syncthreads();
#pragma unroll
        for (int kk = 0; kk < 64; kk += 32) {
            bf16x8 af[4], bg[4];
#pragma unroll
            for (int i = 0; i < 4; ++i)
                af[i] = *(const bf16x8*)&Al[(wm + i * 16 + l16) * 72 + kk + quad * 8];
#pragma unroll
            for (int jj = 0; jj < 4; ++jj)
                bg[jj] = *(const bf16x8*)&Bl[(wn + jj * 16 + l16) * 72 + kk + quad * 8];
#pragma unroll
            for (int i = 0; i < 4; ++i)
#pragma unroll
                for (int jj = 0; jj < 4; ++jj)
                    acc[i][jj] = __builtin_amdgcn_mfma_f32_16x16x32_bf16(
                        af[i], bg[jj], acc[i][jj], 0, 0, 0);
        }
        __syncthreads();
    }

#pragma unroll
    for (int jj = 0; jj < 4; ++jj) {
        int n = n0 + wn + jj * 16 + l16;
        float bv = b_ih[n] + b_hh[n];
#pragma unroll
        for (int i = 0; i < 4; ++i) {
            int mbase = m0 + wm + i * 16 + quad * 4;
#pragma unroll
            for (int r = 0; r < 4; ++r)
                Xp[(size_t)(mbase + r) * 2048 + n] = acc[i][jj][r] + bv;
        }
    }
}

// ---------------------------------------------------------------------------
// W_lin fp32 -> bf16 pre-convert
// ---------------------------------------------------------------------------
__global__ __launch_bounds__(256) void cvt_bf16(
    const float* __restrict__ src, short* __restrict__ dst, int n8)
{
    int i = blockIdx.x * 256 + threadIdx.x;
    if (i < n8)
        *(int4*)&dst[(size_t)i * 8] = ld8_f32_to_bf16(&src[(size_t)i * 8]);
}

// ---------------------------------------------------------------------------
// GEMM2: out[M][N] = A(bf16) @ W[N][K]^T + bias(f32), fp32 out, M-guard.
// BF16B: W already bf16 -> stage both tiles via global_load_lds (16B/lane)
// into UNPADDED [128][64] LDS with XOR swizzle: LDS[row][u] = G[row][u^(row&7)]
// (16B slots), achieved by inverse-swizzling the per-lane GLOBAL source while
// the LDS dest stays linear (rule #21). ds_read applies the same XOR ->
// conflict-free. Fallback (!BF16B): old reg-staged padded path, fp32 inline
// conversion.
// ---------------------------------------------------------------------------
template <bool BF16B>
__global__ __launch_bounds__(256) void gemm_out(
    const short* __restrict__ A,       // M x K bf16
    const void*  __restrict__ Wv,      // N x K (bf16 or f32)
    const float* __restrict__ bias,    // N
    float* __restrict__ C,
    int M, int N, int K)
{
    __shared__ __align__(16) short Al[128 * 72];
    __shared__ __align__(16) short Bl[128 * 72];
    const int tid  = threadIdx.x;
    const int wave = tid >> 6, lane = tid & 63;
    const int quad = lane >> 4, l16 = lane & 15;
    const int m0 = blockIdx.y * 128;
    const int n0 = blockIdx.x * 128;
    const int wm = (wave >> 1) * 64, wn = (wave & 1) * 64;
    const int sr = tid >> 3;
    const int sc = (tid & 7) * 8;

    f32x4 acc[4][4] = {};

    for (int k0 = 0; k0 < K; k0 += 64) {
        if (BF16B) {
            // --- direct-to-LDS staging, 4 passes x (A,B), 16B/lane ---
            const char* Ab = (const char*)A;        // row stride K*2 = 1024 B
            const char* Wb = (const char*)Wv;       // row stride 1024 B
            char* AlB = (char*)Al;
            char* BlB = (char*)Bl;
#pragma unroll
            for (int p = 0; p < 4; ++p) {
                int row = p * 32 + wave * 8 + (lane >> 3);   // 0..127
                int ss  = ((lane & 7) ^ (row & 7)) << 4;     // src slot, swizzled
                int am  = m0 + row; am = (am < M) ? am : (M - 1);
                gload_lds16(Ab + (size_t)am * 1024 + k0 * 2 + ss,
                            AlB + p * 4096 + wave * 1024);
                gload_lds16(Wb + (size_t)(n0 + row) * 1024 + k0 * 2 + ss,
                            BlB + p * 4096 + wave * 1024);
            }
        } else {
#pragma unroll
            for (int p = 0; p < 4; ++p) {
                int r = sr + p * 32;
                int am = m0 + r;
                am = (am < M) ? am : (M - 1);
                *(int4*)&Al[r * 72 + sc] = *(const int4*)&A[(size_t)am * K + k0 + sc];
                *(int4*)&Bl[r * 72 + sc] =
                    ld8_f32_to_bf16(&((const float*)Wv)[(size_t)(n0 + r) * K + k0 + sc]);
            }
        }
        __syncthreads();
#pragma unroll
        for (int kk = 0; kk < 64; kk += 32) {
            bf16x8 af[4], bg[4];
            if (BF16B) {
                const int s_ = (kk >> 3) + quad;            // 16B slot 0..7
#pragma unroll
                for (int i = 0; i < 4; ++i) {
                    int rw = wm + i * 16 + l16;
                    af[i] = *(const bf16x8*)&Al[rw * 64 + ((s_ ^ (rw & 7)) << 3)];
                }
#pragma unroll
                for (int jj = 0; jj < 4; ++jj) {
                    int rw = wn + jj * 16 + l16;
                    bg[jj] = *(const bf16x8*)&Bl[rw * 64 + ((s_ ^ (rw & 7)) << 3)];
                }
            } else {
#pragma unroll
                for (int i = 0; i < 4; ++i)
                    af[i] = *(const bf16x8*)&Al[(wm + i * 16 + l16) * 72 + kk + quad * 8];
#pragma unroll
                for (int jj = 0; jj < 4; ++jj)
                    bg[jj] = *(const bf16x8*)&Bl[(wn + jj * 16 + l16) * 72 + kk + quad * 8];
            }
#pragma unroll
            for (int i = 0; i < 4; ++i)
#pragma unroll
                for (int jj = 0; jj < 4; ++jj)
                    acc[i][jj] = __builtin_amdgcn_mfma_f32_16x16x32_bf16(
                        af[i], bg[jj], acc[i][jj], 0, 0, 0);
        }
        __syncthreads();
    }

#pragma unroll
    for (int jj = 0; jj < 4; ++jj) {
        int n = n0 + wn + jj * 16 + l16;
        float bv = bias[n];
#pragma unroll
        for (int i = 0; i < 4; ++i) {
            int mbase = m0 + wm + i * 16 + quad * 4;
#pragma unroll
            for (int r = 0; r < 4; ++r) {
                int m = mbase + r;
                if (m < M)
                    C[(size_t)m * N + n] = acc[i][jj][r] + bv;
            }
        }
    }
}

// ---------------------------------------------------------------------------
// Persistent LSTM: 32 blocks x 256 thr. Block bx owns h-cols [16bx,16bx+16)
// (gate-cols {s*512+16bx..}, s=0..3). W_hh slice (64x512, bf16) in LDS,
// XOR-swizzled (r3: killed the 16-way conflict). c in VGPRs. h ping-pongs in
// global (bf16): write-through u64 agent stores / L2-bypass u64 agent loads.
// No threadfence anywhere. Barrier: flags[bid]=t+1 after __syncthreads (which
// drains vmcnt -> stores at coherence point); wave-0 lanes spin (bounded).
// r4 schedule (restored): h-load batch -> MFMA -> cell -> publish -> Xp
// prefetch (overlaps the store-ack drain) -> sync/flag/spin.
// __launch_bounds__(256,1): grid=32, 1 block/CU; no VGPR cap.
// ---------------------------------------------------------------------------
#define LSTM_BLOCKS 32

__global__ __launch_bounds__(256, 1) void lstm_persist(
    const float* __restrict__ Xp,     // [59][64][2048] fp32 (in d_out)
    const float* __restrict__ W_hh,   // [2048][512] fp32
    unsigned long long* __restrict__ hbuf, // [2][64][512] bf16 ping-pong
    unsigned long long* __restrict__ dec_h, // [1216][512] bf16 (row = b*19+dec)
    unsigned* __restrict__ flags)     // [32] zeroed per launch
{
    __shared__ __align__(16) short Wl[64 * 512];   // 64 KB, swizzled layout
    __shared__ __align__(16) short Ht[4][16][16];  // 2 KB: per-wave h tile
    const int tid  = threadIdx.x;
    const int wave = tid >> 6, lane = tid & 63;
    const int quad = lane >> 4, l16 = lane & 15;
    const int nb = blockIdx.x * 16;
    const int swz = (l16 & 7) << 3;                // read-side XOR (shorts)

    // one-time: W slice -> LDS (row rr = s*16+col <-> W_hh row s*512+nb+col)
    // write-side XOR uses rr (wave-uniform) -> conflict-free.
#pragma unroll
    for (int it = 0; it < 16; ++it) {
        int rr = (tid >> 6) + it * 4;          // 0..63
        int k  = (tid & 63) * 8;               // 0..504
        int s = rr >> 4, col = rr & 15;
        *(int4*)&Wl[(rr * 512 + k) ^ ((rr & 7) << 3)] =
            ld8_f32_to_bf16(&W_hh[(size_t)(s * 512 + nb + col) * 512 + k]);
    }
    float creg[4] = {0.f, 0.f, 0.f, 0.f};

    // Xp prefetch for t=0 (overlaps the W-LDS staging)
    const int n = nb + l16;
    float xg[4][4];
#pragma unroll
    for (int r = 0; r < 4; ++r) {
        const float* xr = Xp + (size_t)(wave * 16 + quad * 4 + r) * 2048;
        xg[r][0] = xr[n];
        xg[r][1] = xr[512 + n];
        xg[r][2] = xr[1024 + n];
        xg[r][3] = xr[1536 + n];
    }
    __syncthreads();

    for (int t = 0; t < 59; ++t) {
        f32x4 acc[4] = {};
        if (t > 0) {
            // h_in: L2-bypass loads (row m = wave*16+l16). Issue ALL 32 loads
            // as one batch; sched_barrier keeps consumption below the cluster
            // so the whole 256B/thread read costs ~1 MALL round trip.
            const unsigned long long* hrow =
                hbuf + ((size_t)((t & 1) ^ 1) << 13)          // slot * 8192 u64
                     + (size_t)(wave * 16 + l16) * 128 + quad * 2;
            union { unsigned long long q[2]; bf16x8 v; } hu[16];
#pragma unroll
            for (int kk = 0; kk < 16; ++kk) {
                hu[kk].q[0] = __hip_atomic_load(&hrow[kk * 8],
                                 __ATOMIC_RELAXED, __HIP_MEMORY_SCOPE_AGENT);
                hu[kk].q[1] = __hip_atomic_load(&hrow[kk * 8 + 1],
                                 __ATOMIC_RELAXED, __HIP_MEMORY_SCOPE_AGENT);
            }
            __builtin_amdgcn_sched_barrier(0);   // pin: all loads issued first
#pragma unroll
            for (int kk = 0; kk < 16; ++kk) {
#pragma unroll
                for (int s = 0; s < 4; ++s) {
                    bf16x8 bg = *(const bf16x8*)
                        &Wl[((s * 16 + l16) * 512 + kk * 32 + quad * 8) ^ swz];
                    acc[s] = __builtin_amdgcn_mfma_f32_16x16x32_bf16(hu[kk].v, bg, acc[s], 0, 0, 0);
                }
            }
        }
        // cell update (C-layout: row = quad*4+r, col = l16) -> LDS tile
#pragma unroll
        for (int r = 0; r < 4; ++r) {
            float iv = acc[0][r] + xg[r][0];
            float fv = acc[1][r] + xg[r][1];
            float gv = acc[2][r] + xg[r][2];
            float ov = acc[3][r] + xg[r][3];
            float cn = sig_fast(fv) * creg[r] + sig_fast(iv) * tanh_fast(gv);
            float hn = sig_fast(ov) * tanh_fast(cn);
            creg[r] = cn;
            Ht[wave][quad * 4 + r][l16] = f2bf(hn);
        }
        asm volatile("s_waitcnt lgkmcnt(0)" ::: "memory");  // wave-local tile ready
        // publish tile: ONE aligned u64 write-through store per thread
        unsigned long long* hout64 = hbuf + ((size_t)(t & 1) << 13);
        {
            int row = lane >> 2, qp = lane & 3;    // row 0..15, u64-in-row 0..3
            unsigned long long v = *(const unsigned long long*)&Ht[wave][row][qp * 4];
            int m = wave * 16 + row;
            __hip_atomic_store(&hout64[m * 128 + (nb >> 2) + qp], v,
                               __ATOMIC_RELAXED, __HIP_MEMORY_SCOPE_AGENT);
            if (t >= 40)
                dec_h[(size_t)(m * 19 + (t - 40)) * 128 + (nb >> 2) + qp] = v;
        }
        if (t < 58) {
            // Xp prefetch for t+1 BEFORE the barrier: its HBM RTT overlaps
            // the store-ack drain inside __syncthreads (max, not sum).
            float xn_[4][4];
            const float* xt = Xp + (size_t)(t + 1) * 131072;
#pragma unroll
            for (int r = 0; r < 4; ++r) {
                const float* xr = xt + (size_t)(wave * 16 + quad * 4 + r) * 2048;
                xn_[r][0] = xr[n];
                xn_[r][1] = xr[512 + n];
                xn_[r][2] = xr[1024 + n];
                xn_[r][3] = xr[1536 + n];
            }
            // __syncthreads drains vmcnt(0) in every thread -> all h stores
            // of this block are at the coherence point before the flag store.
            __syncthreads();
            if (tid == 0)
                __hip_atomic_store(&flags[blockIdx.x], (unsigned)(t + 1),
                                   __ATOMIC_RELAXED, __HIP_MEMORY_SCOPE_AGENT);
            if (tid < LSTM_BLOCKS) {
                int guard = 0;
                while (__hip_atomic_load(&flags[tid], __ATOMIC_RELAXED,
                                         __HIP_MEMORY_SCOPE_AGENT) < (unsigned)(t + 1)
                       && guard < (1 << 16)) {   // bounded: fail visibly, not hang
                    __builtin_amdgcn_s_sleep(1);
                    ++guard;
                }
            }
            __syncthreads();
#pragma unroll
            for (int r = 0; r < 4; ++r)
#pragma unroll
                for (int g = 0; g < 4; ++g)
                    xg[r][g] = xn_[r][g];
        }
    }
}

// ---------------------------------------------------------------------------
extern "C" void kernel_launch(void* const* d_in, const int* in_sizes, int n_in,
                              void* d_out, int out_size, void* d_ws, size_t ws_size,
                              hipStream_t stream)
{
    (void)in_sizes; (void)n_in; (void)out_size;
    const float* feature   = (const float*)d_in[0];
    const int*   captions  = (const int*)d_in[1];
    const float* embedding = (const float*)d_in[2];
    const float* W_ih      = (const float*)d_in[3];
    const float* W_hh      = (const float*)d_in[4];
    const float* b_ih      = (const float*)d_in[5];
    const float* b_hh      = (const float*)d_in[6];
    const float* W_lin     = (const float*)d_in[7];
    const float* b_lin     = (const float*)d_in[8];
    float* out = (float*)d_out;

    // ws layout
    char* ws = (char*)d_ws;
    unsigned long long* hbuf = (unsigned long long*)(ws); // 2*64*512*2 = 131,072 B
    short*    dech = (short*)(ws + 131072);        // 1216*512*2   = 1,245,184 B
    unsigned* flags = (unsigned*)(ws + 1376256);   // 128 B (32 x u32)
    short*    wbf  = (short*)(ws + 1376512);       // 32000*512*2  = 32,768,000 B
    const bool big = ws_size >= (size_t)1376512 + 32768000;

    // fp32 X_proj lives in d_out (31.5 MB of 155.6 MB); dead before GEMM2.
    float* Xp = (float*)d_out;

    hipMemsetAsync(flags, 0, 256, stream);

    if (big)
        cvt_bf16<<<8000, 256, 0, stream>>>(W_lin, wbf, 2048000);

    gemm_xproj<<<dim3(16, 30), 256, 0, stream>>>(
        feature, captions, embedding, W_ih, b_ih, b_hh, Xp);

    lstm_persist<<<LSTM_BLOCKS, 256, 0, stream>>>(
        Xp, W_hh, hbuf, (unsigned long long*)dech, flags);

    if (big)
        gemm_out<true><<<dim3(250, 10), 256, 0, stream>>>(
            dech, wbf, b_lin, out, 1216, 32000, 512);
    else
        gemm_out<false><<<dim3(250, 10), 256, 0, stream>>>(
            dech, W_lin, b_lin, out, 1216, 32000, 512);
}